// Round 2
// baseline (708.771 us; speedup 1.0000x reference)
//
#include <hip/hip_runtime.h>
#include <stdint.h>

#define NH    32
#define HS    128
#define NPT   2048
#define NT    2112
#define NBLK  1024
#define BS    16
#define MBMAX 32
#define LSEQ  512
#define DMODEL 4096
#define SCALE 0.08838834764831845f

typedef __bf16 bf16x8 __attribute__((ext_vector_type(8)));
typedef float  f32x4  __attribute__((ext_vector_type(4)));

__device__ __forceinline__ unsigned short f2bf(float f) {
    unsigned u = __float_as_uint(f);
    u += 0x7fffu + ((u >> 16) & 1u);          // RNE
    return (unsigned short)(u >> 16);
}
__device__ __forceinline__ unsigned pack2(float a, float b) {
    return (unsigned)f2bf(a) | ((unsigned)f2bf(b) << 16);
}
__device__ __forceinline__ float sel4(const float a[4], int i) {
    float r = a[0];
    r = (i == 1) ? a[1] : r;
    r = (i == 2) ? a[2] : r;
    r = (i == 3) ? a[3] : r;
    return r;
}

// ---------------- winner map: last (max) token writing each cache slot ------
// (init is done host-side via hipMemsetAsync 0xFF -> -1)
__global__ void fill_winner(const int* __restrict__ sm, int* __restrict__ w) {
    int t = blockIdx.x * 256 + threadIdx.x;
    if (t < NT) atomicMax(&w[sm[t]], t);
}

// ---------------- prompt attention: bf16 MFMA flash, 64x64 tiles -----------
// grid 1024 = NSQ*NH*8 qtiles ; block 256 = 4 waves, wave owns 16 q-rows
// v2: Q fragments live in registers (no Qs LDS); K/V tile kt+1 is prefetched
// into registers right after the staging barrier, so HBM/L3 latency hides
// under the whole QK^T+softmax+PV compute phase (T14 async-STAGE split).
#define QKS 136                     // K LDS row stride (bf16), 16B aligned
// V^T row stride 72, XOR token swizzle (bits>=3 only -> no cross-row overlap,
// 4-token writes and 8-token reads stay contiguous)
__device__ __forceinline__ int vtidx(int d, int t) {
    return d * 72 + (t ^ (((d >> 3) & 3) * 8));
}

__global__ __launch_bounds__(256, 2) void prompt_attn(
    const float* __restrict__ q, const float* __restrict__ k,
    const float* __restrict__ v, float* __restrict__ out) {

    __shared__ __align__(16) unsigned short Ks[64 * QKS];
    __shared__ __align__(16) unsigned short Vt[128 * 72 + 32];
    __shared__ __align__(16) unsigned short Ps[4 * 16 * 72];

    const int tid  = threadIdx.x;
    const int lane = tid & 63, wq = tid >> 6;
    const int quad = lane >> 4, m15 = lane & 15;
    const int qt = 7 - (blockIdx.x & 7);       // heavy tiles first
    const int h  = (blockIdx.x >> 3) & 31;
    const int s  = blockIdx.x >> 8;
    const int qbase  = s * LSEQ + qt * 64;
    const int kbase0 = s * LSEQ;

    // ---- Q fragments (pre-scaled) straight into registers ----
    bf16x8 aq[4];
    {
        const float* qr = q + (size_t)(qbase + wq * 16 + m15) * DMODEL + h * HS + quad * 8;
        #pragma unroll
        for (int kc = 0; kc < 4; ++kc) {
            float4 t0 = *(const float4*)(qr + kc * 32);
            float4 t1 = *(const float4*)(qr + kc * 32 + 4);
            union { unsigned u[4]; bf16x8 v; } cv;
            cv.u[0] = pack2(t0.x * SCALE, t0.y * SCALE);
            cv.u[1] = pack2(t0.z * SCALE, t0.w * SCALE);
            cv.u[2] = pack2(t1.x * SCALE, t1.y * SCALE);
            cv.u[3] = pack2(t1.z * SCALE, t1.w * SCALE);
            aq[kc] = cv.v;
        }
    }

    f32x4 O[8];
    #pragma unroll
    for (int i = 0; i < 8; ++i) O[i] = (f32x4){0.f, 0.f, 0.f, 0.f};
    float mrun[4], lrun[4];
    #pragma unroll
    for (int r = 0; r < 4; ++r) { mrun[r] = -1e30f; lrun[r] = 0.f; }

    unsigned short* Pw = Ps + wq * (16 * 72);

    // staging-thread geometry (fixed per thread)
    const int r0 = tid >> 5, c4 = (tid & 31) * 4;          // K staging
    const int gv = tid >> 2, sub = tid & 3;                // V staging
    const int lbase = lane & ~3;

    // ---- preload tile 0 into registers ----
    float4 kreg[8], vreg[8];
    #pragma unroll
    for (int p = 0; p < 8; ++p) {
        int r = r0 + p * 8;
        kreg[p] = *(const float4*)(k + (size_t)(kbase0 + r) * DMODEL + h * HS + c4);
    }
    #pragma unroll
    for (int p = 0; p < 8; ++p) {
        const int tb = (p & 3) * 16, db = (p >> 2) * 64;
        const int tok  = tb + (gv >> 4) * 4 + sub;
        const int dim4 = db + (gv & 15) * 4;
        vreg[p] = *(const float4*)(v + (size_t)(kbase0 + tok) * DMODEL + h * HS + dim4);
    }

    for (int kt = 0; kt <= qt; ++kt) {
        // ---- write K tile (bf16) from regs ----
        #pragma unroll
        for (int p = 0; p < 8; ++p) {
            int r = r0 + p * 8;
            float4 t = kreg[p];
            uint2 w; w.x = pack2(t.x, t.y); w.y = pack2(t.z, t.w);
            *(uint2*)(&Ks[r * QKS + c4]) = w;
        }
        // ---- write V^T (bf16) from regs via in-register 4x4 shfl transpose ----
        #pragma unroll
        for (int p = 0; p < 8; ++p) {
            const int tb = (p & 3) * 16, db = (p >> 2) * 64;
            const int dim4 = db + (gv & 15) * 4;
            float4 t = vreg[p];
            float in[4] = {t.x, t.y, t.z, t.w};
            float rec[4];
            #pragma unroll
            for (int r = 0; r < 4; ++r) {
                float pub = sel4(in, (sub + 4 - r) & 3);
                rec[r] = __shfl(pub, lbase + ((sub + r) & 3));
            }
            float o4[4];
            #pragma unroll
            for (int j = 0; j < 4; ++j) o4[j] = sel4(rec, (j + 4 - sub) & 3);
            const int d  = dim4 + sub;
            const int t0 = tb + (gv >> 4) * 4;
            uint2 w2; w2.x = pack2(o4[0], o4[1]); w2.y = pack2(o4[2], o4[3]);
            *(uint2*)(&Vt[vtidx(d, t0)]) = w2;
        }
        __syncthreads();

        // ---- prefetch tile kt+1 into registers (hides under compute) ----
        if (kt < qt) {
            #pragma unroll
            for (int p = 0; p < 8; ++p) {
                int r = r0 + p * 8;
                kreg[p] = *(const float4*)(k + (size_t)(kbase0 + (kt + 1) * 64 + r) * DMODEL + h * HS + c4);
            }
            #pragma unroll
            for (int p = 0; p < 8; ++p) {
                const int tb = (p & 3) * 16, db = (p >> 2) * 64;
                const int tok  = tb + (gv >> 4) * 4 + sub;
                const int dim4 = db + (gv & 15) * 4;
                vreg[p] = *(const float4*)(v + (size_t)(kbase0 + (kt + 1) * 64 + tok) * DMODEL + h * HS + dim4);
            }
        }

        // ---- QK^T: S[16 x 64] per wave via 16 MFMA ----
        f32x4 S[4];
        #pragma unroll
        for (int nt = 0; nt < 4; ++nt) {
            S[nt] = (f32x4){0.f, 0.f, 0.f, 0.f};
            #pragma unroll
            for (int kc = 0; kc < 4; ++kc) {
                bf16x8 bk = *(const bf16x8*)(&Ks[(nt * 16 + m15) * QKS + kc * 32 + quad * 8]);
                S[nt] = __builtin_amdgcn_mfma_f32_16x16x32_bf16(aq[kc], bk, S[nt], 0, 0, 0);
            }
        }
        // causal mask on diagonal tile (C layout: row = quad*4+reg, col = nt*16+m15)
        if (kt == qt) {
            #pragma unroll
            for (int nt = 0; nt < 4; ++nt) {
                const int C = nt * 16 + m15;
                #pragma unroll
                for (int reg = 0; reg < 4; ++reg) {
                    const int R = wq * 16 + quad * 4 + reg;
                    if (C > R) S[nt][reg] = -1e30f;
                }
            }
        }

        // ---- online softmax per row (row lives in 16 lanes sharing quad) ----
        #pragma unroll
        for (int reg = 0; reg < 4; ++reg) {
            float x = fmaxf(fmaxf(S[0][reg], S[1][reg]), fmaxf(S[2][reg], S[3][reg]));
            x = fmaxf(x, __shfl_xor(x, 1));
            x = fmaxf(x, __shfl_xor(x, 2));
            x = fmaxf(x, __shfl_xor(x, 4));
            x = fmaxf(x, __shfl_xor(x, 8));
            const float mn = fmaxf(mrun[reg], x);
            const float al = __expf(mrun[reg] - mn);
            mrun[reg] = mn;
            float sum = 0.f;
            #pragma unroll
            for (int nt = 0; nt < 4; ++nt) {
                float pv = __expf(S[nt][reg] - mn);
                S[nt][reg] = pv;
                sum += pv;
            }
            sum += __shfl_xor(sum, 1);
            sum += __shfl_xor(sum, 2);
            sum += __shfl_xor(sum, 4);
            sum += __shfl_xor(sum, 8);
            lrun[reg] = lrun[reg] * al + sum;
            #pragma unroll
            for (int n2 = 0; n2 < 8; ++n2) O[n2][reg] *= al;
        }

        // ---- write P (bf16) to wave-private LDS, C layout -> row-major ----
        #pragma unroll
        for (int nt = 0; nt < 4; ++nt) {
            #pragma unroll
            for (int reg = 0; reg < 4; ++reg) {
                float v0 = S[nt][reg];
                float v1 = __shfl_xor(v0, 1);
                if (!(lane & 1))
                    *(unsigned*)(&Pw[(quad * 4 + reg) * 72 + nt * 16 + m15]) = pack2(v0, v1);
            }
        }

        // ---- PV: O[16 x 128] += P[16 x 64] * V[64 x 128] via 16 MFMA ----
        bf16x8 ap[2];
        #pragma unroll
        for (int kc = 0; kc < 2; ++kc)
            ap[kc] = *(const bf16x8*)(&Pw[m15 * 72 + kc * 32 + quad * 8]);
        #pragma unroll
        for (int n2 = 0; n2 < 8; ++n2) {
            #pragma unroll
            for (int kc = 0; kc < 2; ++kc) {
                bf16x8 bv = *(const bf16x8*)(&Vt[vtidx(n2 * 16 + m15, kc * 32 + quad * 8)]);
                O[n2] = __builtin_amdgcn_mfma_f32_16x16x32_bf16(ap[kc], bv, O[n2], 0, 0, 0);
            }
        }
        __syncthreads();   // protect Ks/Vt before next staging write
    }

    // ---- epilogue: divide by l, store fp32 ----
    float inv[4];
    #pragma unroll
    for (int reg = 0; reg < 4; ++reg) inv[reg] = 1.f / lrun[reg];
    #pragma unroll
    for (int n2 = 0; n2 < 8; ++n2) {
        #pragma unroll
        for (int reg = 0; reg < 4; ++reg) {
            out[(size_t)(qbase + wq * 16 + quad * 4 + reg) * DMODEL + h * HS + n2 * 16 + m15] =
                O[n2][reg] * inv[reg];
        }
    }
}

// ---------------- decode: 4-wave split-context flash-decoding --------------
// grid 2048 = GD*NH ; block 256 ; wave w handles KV-blocks w, w+4, ...
// Register-resident: cache layout [d=128][of=16] means the coalesced float4
// at (lane*4 + i*256) holds rows d=(lane>>2)+16i, cols of=(lane&3)*4..+3.
// Columns per lane are FIXED across i, so after the score butterfly-reduce
// (xor 4,8,16,32 over the 16 lanes sharing lane&3) each lane's p[j] multiply
// its own V fragments directly: PV needs no LDS and no shuffles.
// Overrides are lane-parallel gathers (no serial 16-step shfl loop), and the
// next K block is prefetched into registers during the V phase.
__global__ __launch_bounds__(256, 3) void decode_attn(
    const float* __restrict__ q, const float* __restrict__ k, const float* __restrict__ v,
    const float* __restrict__ kcache, const float* __restrict__ vcache,
    const int* __restrict__ bt, const int* __restrict__ cl,
    const int* __restrict__ winner, float* __restrict__ out) {

    __shared__ float pm[4], pl[4];
    __shared__ float pacc[4][128];

    const int tid = threadIdx.x, w = tid >> 6, lane = tid & 63;
    const int g = blockIdx.x >> 5, h = blockIdx.x & 31;
    const int n  = cl[g];
    const int nb = (n + 15) >> 4;

    const int p4 = lane >> 2;        // d-row phase: d = p4 + 16*i
    const int ob = (lane & 3) * 4;   // of (column) base: ob..ob+3

    // q fragment (pre-scaled): 8 values, replicated across each quad
    const float* qp = q + (size_t)(NPT + g) * DMODEL + h * HS;
    float qreg[8];
    #pragma unroll
    for (int i = 0; i < 8; ++i) qreg[i] = qp[p4 + 16 * i] * SCALE;

    float m = -1e30f, l = 0.f;
    float acc[8];
    #pragma unroll
    for (int i = 0; i < 8; ++i) acc[i] = 0.f;

    f32x4 kv[8], vv[8];
    int blk = 0;
    if (w < nb) {
        blk = bt[g * MBMAX + w];
        const float* kb = kcache + ((size_t)blk * NH + h) * (HS * BS);
        #pragma unroll
        for (int i = 0; i < 8; ++i)
            kv[i] = *(const f32x4*)(kb + lane * 4 + i * 256);   // prefetch K[w]
    }

    for (int jb = w; jb < nb; jb += 4) {
        // ---- issue V loads for current block early (overlap with K compute)
        const float* vb = vcache + ((size_t)blk * NH + h) * (HS * BS);
        #pragma unroll
        for (int i = 0; i < 8; ++i)
            vv[i] = *(const f32x4*)(vb + lane * 4 + i * 256);

        // winner slots for this lane's 4 columns (quad-broadcast int4)
        const int4 wt4 = *(const int4*)(winner + blk * BS + ob);
        const int wtj[4] = {wt4.x, wt4.y, wt4.z, wt4.w};
        const bool anyw = __any(wt4.x >= 0 || wt4.y >= 0 || wt4.z >= 0 || wt4.w >= 0);

        // ---- K overrides: lane-parallel gather of fresh rows
        if (anyw) {
            #pragma unroll
            for (int j = 0; j < 4; ++j) {
                if (wtj[j] >= 0) {
                    const float* fr = k + (size_t)wtj[j] * DMODEL + h * HS + p4;
                    #pragma unroll
                    for (int i = 0; i < 8; ++i) kv[i][j] = fr[16 * i];
                }
            }
        }

        // ---- scores: per-lane partial dot over its 8 d-rows
        float s[4];
        #pragma unroll
        for (int j = 0; j < 4; ++j) s[j] = 0.f;
        #pragma unroll
        for (int i = 0; i < 8; ++i) {
            s[0] += qreg[i] * kv[i][0];
            s[1] += qreg[i] * kv[i][1];
            s[2] += qreg[i] * kv[i][2];
            s[3] += qreg[i] * kv[i][3];
        }
        #pragma unroll
        for (int j = 0; j < 4; ++j) {
            s[j] += __shfl_xor(s[j], 4);
            s[j] += __shfl_xor(s[j], 8);
            s[j] += __shfl_xor(s[j], 16);
            s[j] += __shfl_xor(s[j], 32);
            if (jb * 16 + ob + j >= n) s[j] = -1e30f;
        }

        // ---- online softmax (tile stats uniform across the wave)
        float tm = fmaxf(fmaxf(s[0], s[1]), fmaxf(s[2], s[3]));
        tm = fmaxf(tm, __shfl_xor(tm, 1));
        tm = fmaxf(tm, __shfl_xor(tm, 2));
        const float mn = fmaxf(m, tm);
        const float al = __expf(m - mn);
        m = mn;
        float p[4], ps = 0.f;
        #pragma unroll
        for (int j = 0; j < 4; ++j) { p[j] = __expf(s[j] - mn); ps += p[j]; }
        ps += __shfl_xor(ps, 1);
        ps += __shfl_xor(ps, 2);
        l = l * al + ps;
        #pragma unroll
        for (int i = 0; i < 8; ++i) acc[i] *= al;

        // ---- prefetch next K block into (now dead) kv regs
        const int jn = jb + 4;
        if (jn < nb) {
            blk = bt[g * MBMAX + jn];
            const float* kb = kcache + ((size_t)blk * NH + h) * (HS * BS);
            #pragma unroll
            for (int i = 0; i < 8; ++i)
                kv[i] = *(const f32x4*)(kb + lane * 4 + i * 256);
        }

        // ---- V overrides, then PV accumulate (no shuffles, no LDS)
        if (anyw) {
            #pragma unroll
            for (int j = 0; j < 4; ++j) {
                if (wtj[j] >= 0) {
                    const float* fr = v + (size_t)wtj[j] * DMODEL + h * HS + p4;
                    #pragma unroll
                    for (int i = 0; i < 8; ++i) vv[i][j] = fr[16 * i];
                }
            }
        }
        #pragma unroll
        for (int i = 0; i < 8; ++i)
            acc[i] += p[0] * vv[i][0] + p[1] * vv[i][1]
                    + p[2] * vv[i][2] + p[3] * vv[i][3];
    }

    // ---- quad-reduce partial column sums, then 4-wave combine via LDS
    #pragma unroll
    for (int i = 0; i < 8; ++i) {
        acc[i] += __shfl_xor(acc[i], 1);
        acc[i] += __shfl_xor(acc[i], 2);
    }
    if (lane == 0) { pm[w] = m; pl[w] = l; }
    if ((lane & 3) == 0) {
        #pragma unroll
        for (int i = 0; i < 8; ++i) pacc[w][p4 + 16 * i] = acc[i];
    }
    __syncthreads();
    if (tid < 128) {
        const float M = fmaxf(fmaxf(pm[0], pm[1]), fmaxf(pm[2], pm[3]));
        float L = 0.f, A = 0.f;
        #pragma unroll
        for (int w2 = 0; w2 < 4; ++w2) {
            const float e = __expf(pm[w2] - M);
            L += e * pl[w2];
            A += e * pacc[w2][tid];
        }
        out[(size_t)(NPT + g) * DMODEL + h * HS + tid] = A / L;
    }
}

extern "C" void kernel_launch(void* const* d_in, const int* in_sizes, int n_in,
                              void* d_out, int out_size, void* d_ws, size_t ws_size,
                              hipStream_t stream) {
    const float* q  = (const float*)d_in[0];
    const float* k  = (const float*)d_in[1];
    const float* v  = (const float*)d_in[2];
    const float* kc = (const float*)d_in[3];
    const float* vc = (const float*)d_in[4];
    const int* bt   = (const int*)d_in[5];
    const int* cl   = (const int*)d_in[6];
    const int* sm   = (const int*)d_in[7];
    float* out  = (float*)d_out;
    int* winner = (int*)d_ws;   // 16384 ints

    hipMemsetAsync(winner, 0xFF, (size_t)NBLK * BS * sizeof(int), stream);  // -1
    hipLaunchKernelGGL(fill_winner, dim3(9),    dim3(256), 0, stream, sm, winner);
    hipLaunchKernelGGL(prompt_attn, dim3(1024), dim3(256), 0, stream, q, k, v, out);
    hipLaunchKernelGGL(decode_attn, dim3(2048), dim3(256), 0, stream,
                       q, k, v, kc, vc, bt, cl, winner, out);
}

// Round 3
// 668.840 us; speedup vs baseline: 1.0597x; 1.0597x over previous
//
#include <hip/hip_runtime.h>
#include <stdint.h>

#define NH    32
#define HS    128
#define NPT   2048
#define NT    2112
#define NBLK  1024
#define BS    16
#define MBMAX 32
#define LSEQ  512
#define DMODEL 4096
#define SCALE 0.08838834764831845f

typedef __bf16 bf16x8 __attribute__((ext_vector_type(8)));
typedef float  f32x4  __attribute__((ext_vector_type(4)));

__device__ __forceinline__ unsigned short f2bf(float f) {
    unsigned u = __float_as_uint(f);
    u += 0x7fffu + ((u >> 16) & 1u);          // RNE
    return (unsigned short)(u >> 16);
}
__device__ __forceinline__ unsigned pack2(float a, float b) {
    return (unsigned)f2bf(a) | ((unsigned)f2bf(b) << 16);
}
__device__ __forceinline__ float sel4(const float a[4], int i) {
    float r = a[0];
    r = (i == 1) ? a[1] : r;
    r = (i == 2) ? a[2] : r;
    r = (i == 3) ? a[3] : r;
    return r;
}

// ---------------- winner map: last (max) token writing each cache slot ------
// (init is done host-side via hipMemsetAsync 0xFF -> -1)
__global__ void fill_winner(const int* __restrict__ sm, int* __restrict__ w) {
    int t = blockIdx.x * 256 + threadIdx.x;
    if (t < NT) atomicMax(&w[sm[t]], t);
}

// ---------------- fused prompt + decode attention --------------------------
// grid 3072 ; block 256. Role by blockIdx: bid%3==0 -> prompt tile (1024),
// else -> decode (g,h) block (2048). Prompt (MFMA/LDS-bound) and decode
// (memory-latency-bound) are resource-complementary; co-residency overlaps
// them so total ~ max instead of sum. Interleaved mapping puts a mix on
// every CU from dispatch start.
#define QKS 136                     // K LDS row stride (bf16), 16B aligned
// V^T row stride 72, XOR token swizzle (bits>=3 only -> no cross-row overlap,
// 4-token writes and 8-token reads stay contiguous)
__device__ __forceinline__ int vtidx(int d, int t) {
    return d * 72 + (t ^ (((d >> 3) & 3) * 8));
}

__global__ __launch_bounds__(256, 3) void fused_attn(
    const float* __restrict__ q, const float* __restrict__ k, const float* __restrict__ v,
    const float* __restrict__ kcache, const float* __restrict__ vcache,
    const int* __restrict__ bt, const int* __restrict__ cl,
    const int* __restrict__ winner, float* __restrict__ out) {

    // prompt-path LDS (45.1 KB)
    __shared__ __align__(16) unsigned short Ks[64 * QKS];
    __shared__ __align__(16) unsigned short Vt[128 * 72 + 32];
    __shared__ __align__(16) unsigned short Ps[4 * 16 * 72];
    // decode-path LDS (2.1 KB)
    __shared__ float pm[4], pl[4];
    __shared__ float pacc[4][128];

    const int tid  = threadIdx.x;
    const int lane = tid & 63;
    const int bid  = blockIdx.x;
    const int rr   = bid % 3;
    const int bb   = bid / 3;

    if (rr == 0) {
        // ==================== PROMPT path (1024 tiles) ====================
        const int wq = tid >> 6;
        const int quad = lane >> 4, m15 = lane & 15;
        const int qt = 7 - (bb & 7);       // heavy tiles first
        const int h  = (bb >> 3) & 31;
        const int s  = bb >> 8;
        const int qbase  = s * LSEQ + qt * 64;
        const int kbase0 = s * LSEQ;

        // ---- Q fragments (pre-scaled) straight into registers ----
        bf16x8 aq[4];
        {
            const float* qr = q + (size_t)(qbase + wq * 16 + m15) * DMODEL + h * HS + quad * 8;
            #pragma unroll
            for (int kc = 0; kc < 4; ++kc) {
                float4 t0 = *(const float4*)(qr + kc * 32);
                float4 t1 = *(const float4*)(qr + kc * 32 + 4);
                union { unsigned u[4]; bf16x8 v; } cv;
                cv.u[0] = pack2(t0.x * SCALE, t0.y * SCALE);
                cv.u[1] = pack2(t0.z * SCALE, t0.w * SCALE);
                cv.u[2] = pack2(t1.x * SCALE, t1.y * SCALE);
                cv.u[3] = pack2(t1.z * SCALE, t1.w * SCALE);
                aq[kc] = cv.v;
            }
        }

        f32x4 O[8];
        #pragma unroll
        for (int i = 0; i < 8; ++i) O[i] = (f32x4){0.f, 0.f, 0.f, 0.f};
        float mrun[4], lrun[4];
        #pragma unroll
        for (int r = 0; r < 4; ++r) { mrun[r] = -1e30f; lrun[r] = 0.f; }

        unsigned short* Pw = Ps + wq * (16 * 72);

        const int r0 = tid >> 5, c4 = (tid & 31) * 4;          // K staging
        const int gv = tid >> 2, sub = tid & 3;                // V staging
        const int lbase = lane & ~3;

        for (int kt = 0; kt <= qt; ++kt) {
            // ---- stage K tile (bf16) ----
            #pragma unroll
            for (int p = 0; p < 8; ++p) {
                int r = r0 + p * 8;
                float4 t = *(const float4*)(k + (size_t)(kbase0 + kt * 64 + r) * DMODEL + h * HS + c4);
                uint2 w; w.x = pack2(t.x, t.y); w.y = pack2(t.z, t.w);
                *(uint2*)(&Ks[r * QKS + c4]) = w;
            }
            // ---- stage V^T (bf16) via in-register 4x4 shfl transpose ----
            #pragma unroll
            for (int p = 0; p < 8; ++p) {
                const int tb = (p & 3) * 16, db = (p >> 2) * 64;
                const int tok  = tb + (gv >> 4) * 4 + sub;
                const int dim4 = db + (gv & 15) * 4;
                float4 t = *(const float4*)(v + (size_t)(kbase0 + kt * 64 + tok) * DMODEL + h * HS + dim4);
                float in[4] = {t.x, t.y, t.z, t.w};
                float rec[4];
                #pragma unroll
                for (int r = 0; r < 4; ++r) {
                    float pub = sel4(in, (sub + 4 - r) & 3);
                    rec[r] = __shfl(pub, lbase + ((sub + r) & 3));
                }
                float o4[4];
                #pragma unroll
                for (int j = 0; j < 4; ++j) o4[j] = sel4(rec, (j + 4 - sub) & 3);
                const int d  = dim4 + sub;
                const int t0 = tb + (gv >> 4) * 4;
                uint2 w2; w2.x = pack2(o4[0], o4[1]); w2.y = pack2(o4[2], o4[3]);
                *(uint2*)(&Vt[vtidx(d, t0)]) = w2;
            }
            __syncthreads();

            // ---- QK^T: S[16 x 64] per wave via 16 MFMA ----
            f32x4 S[4];
            #pragma unroll
            for (int nt = 0; nt < 4; ++nt) {
                S[nt] = (f32x4){0.f, 0.f, 0.f, 0.f};
                #pragma unroll
                for (int kc = 0; kc < 4; ++kc) {
                    bf16x8 bk = *(const bf16x8*)(&Ks[(nt * 16 + m15) * QKS + kc * 32 + quad * 8]);
                    S[nt] = __builtin_amdgcn_mfma_f32_16x16x32_bf16(aq[kc], bk, S[nt], 0, 0, 0);
                }
            }
            // causal mask on diagonal tile (C layout: row = quad*4+reg, col = nt*16+m15)
            if (kt == qt) {
                #pragma unroll
                for (int nt = 0; nt < 4; ++nt) {
                    const int C = nt * 16 + m15;
                    #pragma unroll
                    for (int reg = 0; reg < 4; ++reg) {
                        const int R = wq * 16 + quad * 4 + reg;
                        if (C > R) S[nt][reg] = -1e30f;
                    }
                }
            }

            // ---- online softmax per row (row lives in 16 lanes sharing quad) ----
            #pragma unroll
            for (int reg = 0; reg < 4; ++reg) {
                float x = fmaxf(fmaxf(S[0][reg], S[1][reg]), fmaxf(S[2][reg], S[3][reg]));
                x = fmaxf(x, __shfl_xor(x, 1));
                x = fmaxf(x, __shfl_xor(x, 2));
                x = fmaxf(x, __shfl_xor(x, 4));
                x = fmaxf(x, __shfl_xor(x, 8));
                const float mn = fmaxf(mrun[reg], x);
                const float al = __expf(mrun[reg] - mn);
                mrun[reg] = mn;
                float sum = 0.f;
                #pragma unroll
                for (int nt = 0; nt < 4; ++nt) {
                    float pv = __expf(S[nt][reg] - mn);
                    S[nt][reg] = pv;
                    sum += pv;
                }
                sum += __shfl_xor(sum, 1);
                sum += __shfl_xor(sum, 2);
                sum += __shfl_xor(sum, 4);
                sum += __shfl_xor(sum, 8);
                lrun[reg] = lrun[reg] * al + sum;
                #pragma unroll
                for (int n2 = 0; n2 < 8; ++n2) O[n2][reg] *= al;
            }

            // ---- write P (bf16) to wave-private LDS, C layout -> row-major ----
            #pragma unroll
            for (int nt = 0; nt < 4; ++nt) {
                #pragma unroll
                for (int reg = 0; reg < 4; ++reg) {
                    float v0 = S[nt][reg];
                    float v1 = __shfl_xor(v0, 1);
                    if (!(lane & 1))
                        *(unsigned*)(&Pw[(quad * 4 + reg) * 72 + nt * 16 + m15]) = pack2(v0, v1);
                }
            }

            // ---- PV: O[16 x 128] += P[16 x 64] * V[64 x 128] via 16 MFMA ----
            bf16x8 ap[2];
            #pragma unroll
            for (int kc = 0; kc < 2; ++kc)
                ap[kc] = *(const bf16x8*)(&Pw[m15 * 72 + kc * 32 + quad * 8]);
            #pragma unroll
            for (int n2 = 0; n2 < 8; ++n2) {
                #pragma unroll
                for (int kc = 0; kc < 2; ++kc) {
                    bf16x8 bv = *(const bf16x8*)(&Vt[vtidx(n2 * 16 + m15, kc * 32 + quad * 8)]);
                    O[n2] = __builtin_amdgcn_mfma_f32_16x16x32_bf16(ap[kc], bv, O[n2], 0, 0, 0);
                }
            }
            __syncthreads();   // protect Ks/Vt before next staging write
        }

        // ---- epilogue: divide by l, store fp32 ----
        float inv[4];
        #pragma unroll
        for (int reg = 0; reg < 4; ++reg) inv[reg] = 1.f / lrun[reg];
        #pragma unroll
        for (int n2 = 0; n2 < 8; ++n2) {
            #pragma unroll
            for (int reg = 0; reg < 4; ++reg) {
                out[(size_t)(qbase + wq * 16 + quad * 4 + reg) * DMODEL + h * HS + n2 * 16 + m15] =
                    O[n2][reg] * inv[reg];
            }
        }
    } else {
        // ==================== DECODE path (2048 blocks) ====================
        // Register-resident flash-decoding; see previous-round comments.
        const int dbid = bb * 2 + (rr - 1);
        const int w = tid >> 6;
        const int g = dbid >> 5, h = dbid & 31;
        const int n  = cl[g];
        const int nb = (n + 15) >> 4;

        const int p4 = lane >> 2;        // d-row phase: d = p4 + 16*i
        const int ob = (lane & 3) * 4;   // of (column) base: ob..ob+3

        const float* qp = q + (size_t)(NPT + g) * DMODEL + h * HS;
        float qreg[8];
        #pragma unroll
        for (int i = 0; i < 8; ++i) qreg[i] = qp[p4 + 16 * i] * SCALE;

        float m = -1e30f, l = 0.f;
        float acc[8];
        #pragma unroll
        for (int i = 0; i < 8; ++i) acc[i] = 0.f;

        f32x4 kv[8], vv[8];
        int blk = 0;
        if (w < nb) {
            blk = bt[g * MBMAX + w];
            const float* kb = kcache + ((size_t)blk * NH + h) * (HS * BS);
            #pragma unroll
            for (int i = 0; i < 8; ++i)
                kv[i] = *(const f32x4*)(kb + lane * 4 + i * 256);   // prefetch K[w]
        }

        for (int jb = w; jb < nb; jb += 4) {
            // ---- issue V loads for current block early
            const float* vb = vcache + ((size_t)blk * NH + h) * (HS * BS);
            #pragma unroll
            for (int i = 0; i < 8; ++i)
                vv[i] = *(const f32x4*)(vb + lane * 4 + i * 256);

            const int4 wt4 = *(const int4*)(winner + blk * BS + ob);
            const int wtj[4] = {wt4.x, wt4.y, wt4.z, wt4.w};
            const bool anyw = __any(wt4.x >= 0 || wt4.y >= 0 || wt4.z >= 0 || wt4.w >= 0);

            // ---- K overrides: lane-parallel gather of fresh rows
            if (anyw) {
                #pragma unroll
                for (int j = 0; j < 4; ++j) {
                    if (wtj[j] >= 0) {
                        const float* fr = k + (size_t)wtj[j] * DMODEL + h * HS + p4;
                        #pragma unroll
                        for (int i = 0; i < 8; ++i) kv[i][j] = fr[16 * i];
                    }
                }
            }

            // ---- scores: per-lane partial dot over its 8 d-rows
            float s[4];
            #pragma unroll
            for (int j = 0; j < 4; ++j) s[j] = 0.f;
            #pragma unroll
            for (int i = 0; i < 8; ++i) {
                s[0] += qreg[i] * kv[i][0];
                s[1] += qreg[i] * kv[i][1];
                s[2] += qreg[i] * kv[i][2];
                s[3] += qreg[i] * kv[i][3];
            }
            #pragma unroll
            for (int j = 0; j < 4; ++j) {
                s[j] += __shfl_xor(s[j], 4);
                s[j] += __shfl_xor(s[j], 8);
                s[j] += __shfl_xor(s[j], 16);
                s[j] += __shfl_xor(s[j], 32);
                if (jb * 16 + ob + j >= n) s[j] = -1e30f;
            }

            // ---- online softmax (tile stats uniform across the wave)
            float tm = fmaxf(fmaxf(s[0], s[1]), fmaxf(s[2], s[3]));
            tm = fmaxf(tm, __shfl_xor(tm, 1));
            tm = fmaxf(tm, __shfl_xor(tm, 2));
            const float mn = fmaxf(m, tm);
            const float al = __expf(m - mn);
            m = mn;
            float p[4], ps = 0.f;
            #pragma unroll
            for (int j = 0; j < 4; ++j) { p[j] = __expf(s[j] - mn); ps += p[j]; }
            ps += __shfl_xor(ps, 1);
            ps += __shfl_xor(ps, 2);
            l = l * al + ps;
            #pragma unroll
            for (int i = 0; i < 8; ++i) acc[i] *= al;

            // ---- prefetch next K block into (now dead) kv regs
            const int jn = jb + 4;
            if (jn < nb) {
                blk = bt[g * MBMAX + jn];
                const float* kb = kcache + ((size_t)blk * NH + h) * (HS * BS);
                #pragma unroll
                for (int i = 0; i < 8; ++i)
                    kv[i] = *(const f32x4*)(kb + lane * 4 + i * 256);
            }

            // ---- V overrides, then PV accumulate (no shuffles, no LDS)
            if (anyw) {
                #pragma unroll
                for (int j = 0; j < 4; ++j) {
                    if (wtj[j] >= 0) {
                        const float* fr = v + (size_t)wtj[j] * DMODEL + h * HS + p4;
                        #pragma unroll
                        for (int i = 0; i < 8; ++i) vv[i][j] = fr[16 * i];
                    }
                }
            }
            #pragma unroll
            for (int i = 0; i < 8; ++i)
                acc[i] += p[0] * vv[i][0] + p[1] * vv[i][1]
                        + p[2] * vv[i][2] + p[3] * vv[i][3];
        }

        // ---- quad-reduce partial column sums, then 4-wave combine via LDS
        #pragma unroll
        for (int i = 0; i < 8; ++i) {
            acc[i] += __shfl_xor(acc[i], 1);
            acc[i] += __shfl_xor(acc[i], 2);
        }
        if (lane == 0) { pm[w] = m; pl[w] = l; }
        if ((lane & 3) == 0) {
            #pragma unroll
            for (int i = 0; i < 8; ++i) pacc[w][p4 + 16 * i] = acc[i];
        }
        __syncthreads();
        if (tid < 128) {
            const float M = fmaxf(fmaxf(pm[0], pm[1]), fmaxf(pm[2], pm[3]));
            float L = 0.f, A = 0.f;
            #pragma unroll
            for (int w2 = 0; w2 < 4; ++w2) {
                const float e = __expf(pm[w2] - M);
                L += e * pl[w2];
                A += e * pacc[w2][tid];
            }
            out[(size_t)(NPT + g) * DMODEL + h * HS + tid] = A / L;
        }
    }
}

extern "C" void kernel_launch(void* const* d_in, const int* in_sizes, int n_in,
                              void* d_out, int out_size, void* d_ws, size_t ws_size,
                              hipStream_t stream) {
    const float* q  = (const float*)d_in[0];
    const float* k  = (const float*)d_in[1];
    const float* v  = (const float*)d_in[2];
    const float* kc = (const float*)d_in[3];
    const float* vc = (const float*)d_in[4];
    const int* bt   = (const int*)d_in[5];
    const int* cl   = (const int*)d_in[6];
    const int* sm   = (const int*)d_in[7];
    float* out  = (float*)d_out;
    int* winner = (int*)d_ws;   // 16384 ints

    hipMemsetAsync(winner, 0xFF, (size_t)NBLK * BS * sizeof(int), stream);  // -1
    hipLaunchKernelGGL(fill_winner, dim3(9),    dim3(256), 0, stream, sm, winner);
    hipLaunchKernelGGL(fused_attn,  dim3(3072), dim3(256), 0, stream,
                       q, k, v, kc, vc, bt, cl, winner, out);
}